// Round 5
// baseline (950.707 us; speedup 1.0000x reference)
//
#include <hip/hip_runtime.h>
#include <hip/hip_bf16.h>
#include <stdint.h>

typedef __bf16 bf16_t;
typedef bf16_t bf16x8 __attribute__((ext_vector_type(8)));
typedef bf16_t bf16x4 __attribute__((ext_vector_type(4)));
typedef float  f32x4  __attribute__((ext_vector_type(4)));

#define AS1(p) ((const __attribute__((address_space(1))) void*)(p))
#define AS3(p) ((__attribute__((address_space(3))) void*)(p))

static constexpr int B_ = 32, S_ = 1024, D_ = 1024, P_ = 4, F_ = 4096;
static constexpr int SPP = S_ / P_;          // 256 rows per (batch, phase) chunk
static constexpr int MP  = B_ * SPP;         // 8192 rows per phase-group

// ---- x: [B,S,D] f32 -> xg: [P][MP][D] bf16 (phase-grouped, contiguous) ----
__global__ void conv_x_kernel(const float* __restrict__ x, bf16_t* __restrict__ xg) {
  const int64_t n4 = (int64_t)B_ * S_ * D_ / 4;
  for (int64_t i = (int64_t)blockIdx.x * blockDim.x + threadIdx.x; i < n4;
       i += (int64_t)gridDim.x * blockDim.x) {
    int64_t e = i << 2;
    int d = (int)(e & (D_ - 1));
    int s = (int)((e >> 10) & (S_ - 1));
    int b = (int)(e >> 20);
    int p = s >> 8;
    int r = (b << 8) | (s & 255);
    const float4 v = ((const float4*)x)[i];
    bf16x4 o;
    o[0] = (bf16_t)v.x; o[1] = (bf16_t)v.y; o[2] = (bf16_t)v.z; o[3] = (bf16_t)v.w;
    *(bf16x4*)&xg[(((int64_t)p * MP + r) << 10) | d] = o;
  }
}

// ---- W: [P][K][N] f32 -> Wt: [P][N][K] bf16 (LDS-tiled transpose) ----
__global__ void conv_wt_kernel(const float* __restrict__ W, bf16_t* __restrict__ Wt,
                               int K, int N) {
  __shared__ bf16_t tile[32][33];
  const int p = blockIdx.z;
  const float* Wp = W + (int64_t)p * K * N;
  bf16_t* Wtp = Wt + (int64_t)p * K * N;
  const int n0 = blockIdx.x * 32, k0 = blockIdx.y * 32;
  const int tx = threadIdx.x & 31, ty = threadIdx.x >> 5;
  #pragma unroll
  for (int j = 0; j < 4; ++j) {
    int kr = ty + j * 8;
    tile[kr][tx] = (bf16_t)Wp[(int64_t)(k0 + kr) * N + n0 + tx];
  }
  __syncthreads();
  #pragma unroll
  for (int j = 0; j < 4; ++j) {
    int nr = ty + j * 8;
    Wtp[(int64_t)(n0 + nr) * K + k0 + tx] = tile[tx][nr];
  }
}

// ====== 256x256 GEMM, read-ahead pipelined 4-phase half-tiles ======
// C[M,N] = A[M,K] * Bt[N,K]^T (+bias, opt ReLU). BM=BN=256, BK=64, 8 waves.
// LDS 128 KiB: At0 At1 Bs0 Bs1 (256x64 bf16 tiles, halves a/b = rows 0-127/128-255).
// Swizzle: (row, cb) stored at row*128 + (cb ^ ((row&7)<<4)); gload_lds dest
// LINEAR, inverse perm on global source (both-sides rule).
//
// Per half-tile (1 barrier per phase; operands read ONE PHASE EARLY so the
// pre-MFMA lgkm wait is latency-hidden; reads spread 12/0/0/12):
//   ph1: read b1,a1 | Q1(a0,b0) | stage A1(t+1) | BAR
//   ph2: Q2(a0,b1) | stage B0(t+2) | BAR
//   ph3: Q3(a1,b0) | stage B1(t+2),A0(t+2) | vmcnt(6) [retires tile t+1] | BAR
//   ph4: prefetch next half's a0,b0 (tile t+1 certified by ph3 vmcnt+BAR) |
//        Q4(a1,b1) | BAR
// WAR: each stage into region X follows (same phase, after) the MFMA whose
// lgkm wait completes this wave's last reads of X; cross-wave ordering by the
// preceding barriers + >=200cy gload-return margin (R3-equivalent discipline).
// vmcnt(6): 14 outstanding at ph3 (prevB:6 + ph1:2 + ph2:2 + ph3:4) -> retire
// 8 oldest = tile t+1's four halves exactly.

__device__ __forceinline__ bf16x8 ldsfrag(const char* region, int row, int cb) {
  return *(const bf16x8*)(region + row * 128 + (cb ^ ((row & 7) << 4)));
}

template<int LDK>
__device__ __forceinline__ void stage_half(const bf16_t* gsrc, char* ldsreg, int t) {
  #pragma unroll
  for (int j = 0; j < 2; ++j) {
    const int idx = j * 512 + t;          // 1024 x 16B = 128 rows x 64 cols bf16
    const int row = idx >> 3;
    const int cb  = ((idx & 7) << 4) ^ ((row & 7) << 4);   // inverse-swizzled src col
    __builtin_amdgcn_global_load_lds(AS1((const char*)(gsrc + (int64_t)row * LDK) + cb),
                                     AS3(ldsreg + idx * 16), 16, 0, 0);
  }
}

#define MFMA_QUAD(AF, BF, MO, NO) \
  do { _Pragma("unroll") for (int m_ = 0; m_ < 4; ++m_) \
       _Pragma("unroll") for (int n_ = 0; n_ < 2; ++n_) \
       _Pragma("unroll") for (int k_ = 0; k_ < 2; ++k_) \
         acc[(MO) + m_][(NO) + n_] = __builtin_amdgcn_mfma_f32_16x16x32_bf16( \
             AF[m_][k_], BF[n_][k_], acc[(MO) + m_][(NO) + n_], 0, 0, 0); } while (0)

#define READ_A4(DST, REG, MO) \
  do { _Pragma("unroll") for (int m_ = 0; m_ < 4; ++m_) \
       _Pragma("unroll") for (int k_ = 0; k_ < 2; ++k_) \
         DST[m_][k_] = ldsfrag(REG, wm * 128 + ((MO) + m_) * 16 + fr, k_ * 64 + hi * 16); } while (0)

#define READ_B2(DST, REG, NO) \
  do { _Pragma("unroll") for (int n_ = 0; n_ < 2; ++n_) \
       _Pragma("unroll") for (int k_ = 0; k_ < 2; ++k_) \
         DST[n_][k_] = ldsfrag(REG, wn * 64 + ((NO) + n_) * 16 + fr, k_ * 64 + hi * 16); } while (0)

#define BAR()   __builtin_amdgcn_s_barrier()
#define SBAR()  __builtin_amdgcn_sched_barrier(0)
#define PRIO(x) __builtin_amdgcn_s_setprio(x)
#define VMCNT6() asm volatile("s_waitcnt vmcnt(6)" ::: "memory")
#define VMCNT0() asm volatile("s_waitcnt vmcnt(0)" ::: "memory")

template<bool RELU, bool OUT_BF16, int KK, int NN>
__global__ __launch_bounds__(512, 2)
void ffgemm8_kernel(const bf16_t* __restrict__ A, const bf16_t* __restrict__ Bt,
                    const float* __restrict__ bias, void* __restrict__ outv, int M) {
  static_assert(KK % 128 == 0, "need even number of 64-wide K tiles");
  __shared__ __align__(16) char smem[131072];
  char* const At0 = smem;
  char* const At1 = smem + 32768;
  char* const Bs0 = smem + 65536;
  char* const Bs1 = smem + 98304;

  const int t = threadIdx.x, lane = t & 63, w = t >> 6;
  const int wm = w >> 2, wn = w & 3;          // 2M x 4N wave grid
  const int fr = lane & 15, hi = lane >> 4;

  // T1: bijective XCD swizzle (nwg % 8 == 0) + 4-row supertile banding for L2
  const int gx = gridDim.x, gy = gridDim.y;
  const int nwg = gx * gy * (int)gridDim.z;
  const int id  = ((int)blockIdx.z * gy + (int)blockIdx.y) * gx + (int)blockIdx.x;
  const int swz = (id & 7) * (nwg >> 3) + (id >> 3);
  const int per_p = gx * gy;
  const int p  = swz / per_p;
  const int q  = swz % per_p;
  const int band = q / (gx * 4), qq = q % (gx * 4);
  const int bx = qq >> 2, by = band * 4 + (qq & 3);

  const int tile_m = by * 256, tile_n = bx * 256;
  const bf16_t* Ab = A  + (int64_t)p * M  * KK + (int64_t)tile_m * KK;
  const bf16_t* Bb = Bt + (int64_t)p * NN * KK + (int64_t)tile_n * KK;
  const float* biasp = bias + (int64_t)p * NN;

  f32x4 acc[8][4] = {};
  constexpr int NI = KK / 128;

  bf16x8 a0[4][2], a1[4][2], b0[2][2], b1[2][2];

  // ---- prologue: tile0 full -> buf0; tile1 B0,B1,A0 -> buf1 (6 insts in flight) ----
  stage_half<KK>(Ab,                          At0,          t);
  stage_half<KK>(Ab + (int64_t)128 * KK,      At0 + 16384,  t);
  stage_half<KK>(Bb,                          Bs0,          t);
  stage_half<KK>(Bb + (int64_t)128 * KK,      Bs0 + 16384,  t);
  stage_half<KK>(Bb + 64,                     Bs1,          t);
  stage_half<KK>(Bb + (int64_t)128 * KK + 64, Bs1 + 16384,  t);
  stage_half<KK>(Ab + 64,                     At1,          t);
  VMCNT6();          // tile0's 8 loads landed; Bs1ab+At1a (6) in flight
  BAR(); SBAR();
  READ_A4(a0, At0, 0); READ_B2(b0, Bs0, 0);   // prefetch Q1 operands of tile0

  for (int i = 0; i < NI; ++i) {
    const int k0 = i * 128;                  // tile 2i @ k0, tile 2i+1 @ k0+64
    const bool more = (i < NI - 1);

    // ============ half A: tile 2i from buf0 ============
    // ph1: read b1,a1 | Q1 | stage A1(t2i+1)->At1b | BAR
    READ_B2(b1, Bs0, 2); READ_A4(a1, At0, 4);
    PRIO(1); MFMA_QUAD(a0, b0, 0, 0); PRIO(0);
    stage_half<KK>(Ab + (int64_t)128 * KK + (k0 + 64), At1 + 16384, t);
    BAR(); SBAR();
    // ph2: Q2 | stage B0(t2i+2)->Bs0a | BAR
    PRIO(1); MFMA_QUAD(a0, b1, 0, 2); PRIO(0);
    if (more) stage_half<KK>(Bb + (k0 + 128), Bs0, t);
    BAR(); SBAR();
    // ph3: Q3 | stage B1,A0(t2i+2) | vmcnt retires tile 2i+1 | BAR
    PRIO(1); MFMA_QUAD(a1, b0, 4, 0); PRIO(0);
    if (more) { stage_half<KK>(Bb + (int64_t)128 * KK + (k0 + 128), Bs0 + 16384, t);
                stage_half<KK>(Ab + (k0 + 128), At0, t); }
    if (more) VMCNT6(); else VMCNT0();
    BAR(); SBAR();
    // ph4: prefetch half-B operands (tile 2i+1 certified) | Q4 | BAR
    READ_A4(a0, At1, 0); READ_B2(b0, Bs1, 0);
    PRIO(1); MFMA_QUAD(a1, b1, 4, 2); PRIO(0);
    BAR(); SBAR();

    // ============ half B: tile 2i+1 from buf1 ============
    // ph1: read b1,a1 | Q1 | stage A1(t2i+2)->At0b | BAR
    READ_B2(b1, Bs1, 2); READ_A4(a1, At1, 4);
    PRIO(1); MFMA_QUAD(a0, b0, 0, 0); PRIO(0);
    if (more) stage_half<KK>(Ab + (int64_t)128 * KK + (k0 + 128), At0 + 16384, t);
    BAR(); SBAR();
    // ph2: Q2 | stage B0(t2i+3)->Bs1a | BAR
    PRIO(1); MFMA_QUAD(a0, b1, 0, 2); PRIO(0);
    if (more) stage_half<KK>(Bb + (k0 + 192), Bs1, t);
    BAR(); SBAR();
    // ph3: Q3 | stage B1,A0(t2i+3) | vmcnt retires tile 2i+2 | BAR
    PRIO(1); MFMA_QUAD(a1, b0, 4, 0); PRIO(0);
    if (more) { stage_half<KK>(Bb + (int64_t)128 * KK + (k0 + 192), Bs1 + 16384, t);
                stage_half<KK>(Ab + (k0 + 192), At1, t); }
    if (more) VMCNT6(); else VMCNT0();
    BAR(); SBAR();
    // ph4: prefetch next half-A operands | Q4 | BAR
    if (more) { READ_A4(a0, At0, 0); READ_B2(b0, Bs0, 0); }
    PRIO(1); MFMA_QUAD(a1, b1, 4, 2); PRIO(0);
    BAR(); SBAR();
  }

  // ---- epilogue: C/D layout col=lane&15, row=(lane>>4)*4+j ----
  float bv[4];
  #pragma unroll
  for (int n = 0; n < 4; ++n) bv[n] = biasp[tile_n + wn * 64 + n * 16 + fr];
  if (OUT_BF16) {
    bf16_t* out = (bf16_t*)outv + (int64_t)p * M * NN;
    #pragma unroll
    for (int m = 0; m < 8; ++m)
      #pragma unroll
      for (int j = 0; j < 4; ++j) {
        const int row = tile_m + wm * 128 + m * 16 + hi * 4 + j;
        #pragma unroll
        for (int n = 0; n < 4; ++n) {
          const int col = tile_n + wn * 64 + n * 16 + fr;
          float v = acc[m][n][j] + bv[n];
          if (RELU) v = fmaxf(v, 0.0f);
          out[(int64_t)row * NN + col] = (bf16_t)v;
        }
      }
  } else {
    float* out = (float*)outv;
    #pragma unroll
    for (int m = 0; m < 8; ++m)
      #pragma unroll
      for (int j = 0; j < 4; ++j) {
        const int row = tile_m + wm * 128 + m * 16 + hi * 4 + j;
        const int grow = ((row >> 8) << 10) + p * SPP + (row & 255);
        #pragma unroll
        for (int n = 0; n < 4; ++n) {
          const int col = tile_n + wn * 64 + n * 16 + fr;
          out[(int64_t)grow * NN + col] = acc[m][n][j] + bv[n];
        }
      }
  }
}

extern "C" void kernel_launch(void* const* d_in, const int* in_sizes, int n_in,
                              void* d_out, int out_size, void* d_ws, size_t ws_size,
                              hipStream_t stream) {
  (void)in_sizes; (void)n_in; (void)out_size; (void)ws_size;
  const float* x  = (const float*)d_in[0];
  const float* W1 = (const float*)d_in[1];
  const float* b1 = (const float*)d_in[2];
  const float* W2 = (const float*)d_in[3];
  const float* b2 = (const float*)d_in[4];
  // d_in[5] = phases: unused — static contiguous equal partition (reshape).
  float* y = (float*)d_out;

  char* ws = (char*)d_ws;
  bf16_t* xg = (bf16_t*)ws;                                   // 64 MiB  [P][8192][1024] bf16
  bf16_t* wt = (bf16_t*)(ws + (size_t)64 * 1024 * 1024);      // 32 MiB  [N][K] bf16 (W1t then W2t)
  bf16_t* h  = (bf16_t*)(ws + (size_t)96 * 1024 * 1024);      // 256 MiB [P][8192][4096] bf16

  conv_x_kernel<<<2048, 256, 0, stream>>>(x, xg);
  conv_wt_kernel<<<dim3(F_ / 32, D_ / 32, P_), 256, 0, stream>>>(W1, wt, D_, F_);
  ffgemm8_kernel<true, true, 1024, 4096><<<dim3(F_ / 256, MP / 256, P_), 512, 0, stream>>>(
      xg, wt, b1, h, MP);
  conv_wt_kernel<<<dim3(D_ / 32, F_ / 32, P_), 256, 0, stream>>>(W2, wt, F_, D_);
  ffgemm8_kernel<false, false, 4096, 1024><<<dim3(D_ / 256, MP / 256, P_), 512, 0, stream>>>(
      h, wt, b2, y, MP);
}

// Round 6
// 576.375 us; speedup vs baseline: 1.6495x; 1.6495x over previous
//
#include <hip/hip_runtime.h>
#include <hip/hip_bf16.h>
#include <stdint.h>

typedef __bf16 bf16_t;
typedef bf16_t bf16x8 __attribute__((ext_vector_type(8)));
typedef bf16_t bf16x4 __attribute__((ext_vector_type(4)));
typedef float  f32x4  __attribute__((ext_vector_type(4)));

#define AS1(p) ((const __attribute__((address_space(1))) void*)(p))
#define AS3(p) ((__attribute__((address_space(3))) void*)(p))

static constexpr int B_ = 32, S_ = 1024, D_ = 1024, P_ = 4, F_ = 4096;
static constexpr int SPP = S_ / P_;          // 256 rows per (batch, phase) chunk
static constexpr int MP  = B_ * SPP;         // 8192 rows per phase-group

// ---- x: [B,S,D] f32 -> xg: [P][MP][D] bf16 (phase-grouped, contiguous) ----
__global__ void conv_x_kernel(const float* __restrict__ x, bf16_t* __restrict__ xg) {
  const int64_t n4 = (int64_t)B_ * S_ * D_ / 4;
  for (int64_t i = (int64_t)blockIdx.x * blockDim.x + threadIdx.x; i < n4;
       i += (int64_t)gridDim.x * blockDim.x) {
    int64_t e = i << 2;
    int d = (int)(e & (D_ - 1));
    int s = (int)((e >> 10) & (S_ - 1));
    int b = (int)(e >> 20);
    int p = s >> 8;
    int r = (b << 8) | (s & 255);
    const float4 v = ((const float4*)x)[i];
    bf16x4 o;
    o[0] = (bf16_t)v.x; o[1] = (bf16_t)v.y; o[2] = (bf16_t)v.z; o[3] = (bf16_t)v.w;
    *(bf16x4*)&xg[(((int64_t)p * MP + r) << 10) | d] = o;
  }
}

// ---- W: [P][K][N] f32 -> Wt: [P][N][K] bf16 (LDS-tiled transpose) ----
__global__ void conv_wt_kernel(const float* __restrict__ W, bf16_t* __restrict__ Wt,
                               int K, int N) {
  __shared__ bf16_t tile[32][33];
  const int p = blockIdx.z;
  const float* Wp = W + (int64_t)p * K * N;
  bf16_t* Wtp = Wt + (int64_t)p * K * N;
  const int n0 = blockIdx.x * 32, k0 = blockIdx.y * 32;
  const int tx = threadIdx.x & 31, ty = threadIdx.x >> 5;
  #pragma unroll
  for (int j = 0; j < 4; ++j) {
    int kr = ty + j * 8;
    tile[kr][tx] = (bf16_t)Wp[(int64_t)(k0 + kr) * N + n0 + tx];
  }
  __syncthreads();
  #pragma unroll
  for (int j = 0; j < 4; ++j) {
    int nr = ty + j * 8;
    Wtp[(int64_t)(n0 + nr) * K + k0 + tx] = tile[tx][nr];
  }
}

// ================= 256x256 8-phase GEMM (T1+T2+T3+T4+T5) ==================
// C[M,N] = A[M,K] * Bt[N,K]^T (+bias, opt ReLU). BM=BN=256, BK=64, 8 waves.
// LDS 128 KiB: At0 At1 Bs0 Bs1, each a 256x64 bf16 tile (32 KiB, two halves).
// Swizzle: (row, cb) stored at row*128 + (cb ^ ((row&7)<<4)); gload_lds dest
// LINEAR, inverse perm applied to the global source (both-sides rule).
//
// R6 change vs R3: NO explicit lgkmcnt drains. Reads are issued k0-group
// first (sched_barrier-pinned), MFMAs run k-outermost, so the compiler's
// dependency-driven counted lgkmcnt waits drip (7..0) and k1-read service
// hides under k0 MFMAs. Barrier/stage/vmcnt structure is BIT-IDENTICAL to R3
// (WAR proof: compiler lgkm waits complete each wave's reads before its
// MFMAs, hence before the closing barrier that gates the overwriting stage):
//   ph1: A1(t+1)->At1b   ph3: B0,B1(t+2)->Bs0
//   ph4: A0(t+2)->At0a; vmcnt(6) retires tile t+1
//   ph5: A1(t+2)->At0b   ph7: B0,B1(t+3)->Bs1
//   ph8: A0(t+3)->At1a; vmcnt(6) retires tile t+2

__device__ __forceinline__ bf16x8 ldsfrag(const char* region, int row, int cb) {
  return *(const bf16x8*)(region + row * 128 + (cb ^ ((row & 7) << 4)));
}

template<int LDK>
__device__ __forceinline__ void stage_half(const bf16_t* gsrc, char* ldsreg, int t) {
  #pragma unroll
  for (int j = 0; j < 2; ++j) {
    const int idx = j * 512 + t;          // 1024 x 16B = 128 rows x 64 cols bf16
    const int row = idx >> 3;
    const int cb  = ((idx & 7) << 4) ^ ((row & 7) << 4);   // inverse-swizzled src col
    __builtin_amdgcn_global_load_lds(AS1((const char*)(gsrc + (int64_t)row * LDK) + cb),
                                     AS3(ldsreg + idx * 16), 16, 0, 0);
  }
}

// k-outermost MFMA: operand consumption order matches k-grouped read order.
#define MFMA_QUAD(AF, BF, MO, NO) \
  do { _Pragma("unroll") for (int k_ = 0; k_ < 2; ++k_) \
       _Pragma("unroll") for (int m_ = 0; m_ < 4; ++m_) \
       _Pragma("unroll") for (int n_ = 0; n_ < 2; ++n_) \
         acc[(MO) + m_][(NO) + n_] = __builtin_amdgcn_mfma_f32_16x16x32_bf16( \
             AF[m_][k_], BF[n_][k_], acc[(MO) + m_][(NO) + n_], 0, 0, 0); } while (0)

#define READ_A4K(DST, REG, MO, KS) \
  do { _Pragma("unroll") for (int m_ = 0; m_ < 4; ++m_) \
         DST[m_][KS] = ldsfrag(REG, wm * 128 + ((MO) + m_) * 16 + fr, (KS) * 64 + hi * 16); } while (0)

#define READ_B2K(DST, REG, NO, KS) \
  do { _Pragma("unroll") for (int n_ = 0; n_ < 2; ++n_) \
         DST[n_][KS] = ldsfrag(REG, wn * 64 + ((NO) + n_) * 16 + fr, (KS) * 64 + hi * 16); } while (0)

#define BAR()   __builtin_amdgcn_s_barrier()
#define SBAR()  __builtin_amdgcn_sched_barrier(0)
#define PRIO(x) __builtin_amdgcn_s_setprio(x)
#define VMCNT6() asm volatile("s_waitcnt vmcnt(6)" ::: "memory")
#define VMCNT0() asm volatile("s_waitcnt vmcnt(0)" ::: "memory")

template<bool RELU, bool OUT_BF16, int KK, int NN>
__global__ __launch_bounds__(512, 2)
void ffgemm8_kernel(const bf16_t* __restrict__ A, const bf16_t* __restrict__ Bt,
                    const float* __restrict__ bias, void* __restrict__ outv, int M) {
  static_assert(KK % 128 == 0, "need even number of 64-wide K tiles");
  __shared__ __align__(16) char smem[131072];
  char* const At0 = smem;
  char* const At1 = smem + 32768;
  char* const Bs0 = smem + 65536;
  char* const Bs1 = smem + 98304;

  const int t = threadIdx.x, lane = t & 63, w = t >> 6;
  const int wm = w >> 2, wn = w & 3;          // 2M x 4N wave grid
  const int fr = lane & 15, hi = lane >> 4;

  // T1: bijective XCD swizzle (nwg % 8 == 0) + 4-row supertile banding for L2
  const int gx = gridDim.x, gy = gridDim.y;
  const int nwg = gx * gy * (int)gridDim.z;
  const int id  = ((int)blockIdx.z * gy + (int)blockIdx.y) * gx + (int)blockIdx.x;
  const int swz = (id & 7) * (nwg >> 3) + (id >> 3);
  const int per_p = gx * gy;
  const int p  = swz / per_p;
  const int q  = swz % per_p;
  const int band = q / (gx * 4), qq = q % (gx * 4);
  const int bx = qq >> 2, by = band * 4 + (qq & 3);

  const int tile_m = by * 256, tile_n = bx * 256;
  const bf16_t* Ab = A  + (int64_t)p * M  * KK + (int64_t)tile_m * KK;
  const bf16_t* Bb = Bt + (int64_t)p * NN * KK + (int64_t)tile_n * KK;
  const float* biasp = bias + (int64_t)p * NN;

  f32x4 acc[8][4] = {};
  constexpr int NI = KK / 128;

  // ---- prologue: tile0 (A0,A1,B0,B1) -> buf0; tile1 (B0,B1,A0) -> buf1 ----
  stage_half<KK>(Ab,                          At0,          t);
  stage_half<KK>(Ab + (int64_t)128 * KK,      At0 + 16384,  t);
  stage_half<KK>(Bb,                          Bs0,          t);
  stage_half<KK>(Bb + (int64_t)128 * KK,      Bs0 + 16384,  t);
  stage_half<KK>(Bb + 64,                     Bs1,          t);
  stage_half<KK>(Bb + (int64_t)128 * KK + 64, Bs1 + 16384,  t);
  stage_half<KK>(Ab + 64,                     At1,          t);
  VMCNT6();          // tile0's 8 loads landed; tile1's B0,B1,A0 in flight
  BAR(); SBAR();

  for (int i = 0; i < NI; ++i) {
    const int k0 = i * 128;                  // tile 2i @ k0, tile 2i+1 @ k0+64
    const bool more = (i < NI - 1);
    bf16x8 a0[4][2], a1[4][2], b0[2][2], b1[2][2];

    // ph1: reads(a0,b0 k-grouped) | stage A1(t2i+1)->At1b | Q1
    READ_A4K(a0, At0, 0, 0); READ_B2K(b0, Bs0, 0, 0); SBAR();
    READ_A4K(a0, At0, 0, 1); READ_B2K(b0, Bs0, 0, 1); SBAR();
    stage_half<KK>(Ab + (int64_t)128 * KK + (k0 + 64), At1 + 16384, t);
    BAR(); SBAR(); PRIO(1); MFMA_QUAD(a0, b0, 0, 0); PRIO(0); BAR(); SBAR();
    // ph2: reads(b1) | Q2
    READ_B2K(b1, Bs0, 2, 0); SBAR(); READ_B2K(b1, Bs0, 2, 1); SBAR();
    BAR(); SBAR(); PRIO(1); MFMA_QUAD(a0, b1, 0, 2); PRIO(0); BAR(); SBAR();
    // ph3: reads(a1) | stage B0,B1(t2i+2)->Bs0 | Q3
    READ_A4K(a1, At0, 4, 0); SBAR(); READ_A4K(a1, At0, 4, 1); SBAR();
    if (more) { stage_half<KK>(Bb + (k0 + 128), Bs0, t);
                stage_half<KK>(Bb + (int64_t)128 * KK + (k0 + 128), Bs0 + 16384, t); }
    BAR(); SBAR(); PRIO(1); MFMA_QUAD(a1, b0, 4, 0); PRIO(0); BAR(); SBAR();
    // ph4: stage A0(t2i+2)->At0a | Q4 | vmcnt retires tile 2i+1
    if (more) stage_half<KK>(Ab + (k0 + 128), At0, t);
    BAR(); SBAR(); PRIO(1); MFMA_QUAD(a1, b1, 4, 2); PRIO(0);
    if (more) VMCNT6(); else VMCNT0();
    BAR(); SBAR();

    // ph5: reads(a0,b0 from buf1) | stage A1(t2i+2)->At0b | Q1'
    READ_A4K(a0, At1, 0, 0); READ_B2K(b0, Bs1, 0, 0); SBAR();
    READ_A4K(a0, At1, 0, 1); READ_B2K(b0, Bs1, 0, 1); SBAR();
    if (more) stage_half<KK>(Ab + (int64_t)128 * KK + (k0 + 128), At0 + 16384, t);
    BAR(); SBAR(); PRIO(1); MFMA_QUAD(a0, b0, 0, 0); PRIO(0); BAR(); SBAR();
    // ph6: reads(b1) | Q2'
    READ_B2K(b1, Bs1, 2, 0); SBAR(); READ_B2K(b1, Bs1, 2, 1); SBAR();
    BAR(); SBAR(); PRIO(1); MFMA_QUAD(a0, b1, 0, 2); PRIO(0); BAR(); SBAR();
    // ph7: reads(a1) | stage B0,B1(t2i+3)->Bs1 | Q3'
    READ_A4K(a1, At1, 4, 0); SBAR(); READ_A4K(a1, At1, 4, 1); SBAR();
    if (more) { stage_half<KK>(Bb + (k0 + 192), Bs1, t);
                stage_half<KK>(Bb + (int64_t)128 * KK + (k0 + 192), Bs1 + 16384, t); }
    BAR(); SBAR(); PRIO(1); MFMA_QUAD(a1, b0, 4, 0); PRIO(0); BAR(); SBAR();
    // ph8: stage A0(t2i+3)->At1a | Q4' | vmcnt retires tile 2i+2
    if (more) stage_half<KK>(Ab + (k0 + 192), At1, t);
    BAR(); SBAR(); PRIO(1); MFMA_QUAD(a1, b1, 4, 2); PRIO(0);
    if (more) VMCNT6(); else VMCNT0();
    BAR(); SBAR();
  }

  // ---- epilogue: C/D layout col=lane&15, row=(lane>>4)*4+j ----
  float bv[4];
  #pragma unroll
  for (int n = 0; n < 4; ++n) bv[n] = biasp[tile_n + wn * 64 + n * 16 + fr];
  if (OUT_BF16) {
    bf16_t* out = (bf16_t*)outv + (int64_t)p * M * NN;
    #pragma unroll
    for (int m = 0; m < 8; ++m)
      #pragma unroll
      for (int j = 0; j < 4; ++j) {
        const int row = tile_m + wm * 128 + m * 16 + hi * 4 + j;
        #pragma unroll
        for (int n = 0; n < 4; ++n) {
          const int col = tile_n + wn * 64 + n * 16 + fr;
          float v = acc[m][n][j] + bv[n];
          if (RELU) v = fmaxf(v, 0.0f);
          out[(int64_t)row * NN + col] = (bf16_t)v;
        }
      }
  } else {
    float* out = (float*)outv;
    #pragma unroll
    for (int m = 0; m < 8; ++m)
      #pragma unroll
      for (int j = 0; j < 4; ++j) {
        const int row = tile_m + wm * 128 + m * 16 + hi * 4 + j;
        const int grow = ((row >> 8) << 10) + p * SPP + (row & 255);
        #pragma unroll
        for (int n = 0; n < 4; ++n) {
          const int col = tile_n + wn * 64 + n * 16 + fr;
          out[(int64_t)grow * NN + col] = acc[m][n][j] + bv[n];
        }
      }
  }
}

extern "C" void kernel_launch(void* const* d_in, const int* in_sizes, int n_in,
                              void* d_out, int out_size, void* d_ws, size_t ws_size,
                              hipStream_t stream) {
  (void)in_sizes; (void)n_in; (void)out_size; (void)ws_size;
  const float* x  = (const float*)d_in[0];
  const float* W1 = (const float*)d_in[1];
  const float* b1 = (const float*)d_in[2];
  const float* W2 = (const float*)d_in[3];
  const float* b2 = (const float*)d_in[4];
  // d_in[5] = phases: unused — static contiguous equal partition (reshape).
  float* y = (float*)d_out;

  char* ws = (char*)d_ws;
  bf16_t* xg = (bf16_t*)ws;                                   // 64 MiB  [P][8192][1024] bf16
  bf16_t* wt = (bf16_t*)(ws + (size_t)64 * 1024 * 1024);      // 32 MiB  [N][K] bf16 (W1t then W2t)
  bf16_t* h  = (bf16_t*)(ws + (size_t)96 * 1024 * 1024);      // 256 MiB [P][8192][4096] bf16

  conv_x_kernel<<<2048, 256, 0, stream>>>(x, xg);
  conv_wt_kernel<<<dim3(F_ / 32, D_ / 32, P_), 256, 0, stream>>>(W1, wt, D_, F_);
  ffgemm8_kernel<true, true, 1024, 4096><<<dim3(F_ / 256, MP / 256, P_), 512, 0, stream>>>(
      xg, wt, b1, h, MP);
  conv_wt_kernel<<<dim3(D_ / 32, F_ / 32, P_), 256, 0, stream>>>(W2, wt, F_, D_);
  ffgemm8_kernel<false, false, 4096, 1024><<<dim3(D_ / 256, MP / 256, P_), 512, 0, stream>>>(
      h, wt, b2, y, MP);
}

// Round 7
// 552.599 us; speedup vs baseline: 1.7204x; 1.0430x over previous
//
#include <hip/hip_runtime.h>
#include <hip/hip_bf16.h>
#include <stdint.h>

typedef __bf16 bf16_t;
typedef bf16_t bf16x8 __attribute__((ext_vector_type(8)));
typedef bf16_t bf16x4 __attribute__((ext_vector_type(4)));
typedef float  f32x4  __attribute__((ext_vector_type(4)));

#define AS1(p) ((const __attribute__((address_space(1))) void*)(p))
#define AS3(p) ((__attribute__((address_space(3))) void*)(p))

static constexpr int B_ = 32, S_ = 1024, D_ = 1024, P_ = 4, F_ = 4096;
static constexpr int SPP = S_ / P_;          // 256 rows per (batch, phase) chunk
static constexpr int MP  = B_ * SPP;         // 8192 rows per phase-group

// ---- x: [B,S,D] f32 -> xg: [P][MP][D] bf16 (phase-grouped, contiguous) ----
__global__ void conv_x_kernel(const float* __restrict__ x, bf16_t* __restrict__ xg) {
  const int64_t n4 = (int64_t)B_ * S_ * D_ / 4;
  for (int64_t i = (int64_t)blockIdx.x * blockDim.x + threadIdx.x; i < n4;
       i += (int64_t)gridDim.x * blockDim.x) {
    int64_t e = i << 2;
    int d = (int)(e & (D_ - 1));
    int s = (int)((e >> 10) & (S_ - 1));
    int b = (int)(e >> 20);
    int p = s >> 8;
    int r = (b << 8) | (s & 255);
    const float4 v = ((const float4*)x)[i];
    bf16x4 o;
    o[0] = (bf16_t)v.x; o[1] = (bf16_t)v.y; o[2] = (bf16_t)v.z; o[3] = (bf16_t)v.w;
    *(bf16x4*)&xg[(((int64_t)p * MP + r) << 10) | d] = o;
  }
}

// ---- W: [P][K][N] f32 -> Wt: [P][N][K] bf16 (LDS-tiled transpose) ----
__global__ void conv_wt_kernel(const float* __restrict__ W, bf16_t* __restrict__ Wt,
                               int K, int N) {
  __shared__ bf16_t tile[32][33];
  const int p = blockIdx.z;
  const float* Wp = W + (int64_t)p * K * N;
  bf16_t* Wtp = Wt + (int64_t)p * K * N;
  const int n0 = blockIdx.x * 32, k0 = blockIdx.y * 32;
  const int tx = threadIdx.x & 31, ty = threadIdx.x >> 5;
  #pragma unroll
  for (int j = 0; j < 4; ++j) {
    int kr = ty + j * 8;
    tile[kr][tx] = (bf16_t)Wp[(int64_t)(k0 + kr) * N + n0 + tx];
  }
  __syncthreads();
  #pragma unroll
  for (int j = 0; j < 4; ++j) {
    int nr = ty + j * 8;
    Wtp[(int64_t)(n0 + nr) * K + k0 + tx] = tile[tx][nr];
  }
}

// ====== 256x256 GEMM, read-one-phase-ahead pipeline (R7) ======
// C[M,N] = A[M,K] * Bt[N,K]^T (+bias, opt ReLU). BM=BN=256, BK=64, 8 waves.
// LDS 128 KiB: At0 At1 Bs0 Bs1 (256x64 bf16 tiles; halves a/b = rows 0-127/128-255).
// Swizzle: (row, cb) stored at row*128 + (cb ^ ((row&7)<<4)); gload_lds dest
// LINEAR, inverse perm on the global source (both-sides rule).
//
// Per half-tile, 4 phases, ONE barrier each. Quad_k's operands were read in
// phase k-1, so the compiler's dependency-driven counted lgkmcnt wait before
// each MFMA cluster is covered by the previous cluster + barrier. Only phA's
// 12 reads are exposed (buffer certified at the preceding vmcnt+BAR):
//   phA: read a0,b0 (12) | Q1 | read b1 (4) | stage[slot1] | SBAR BAR
//   phB: Q2 | read a1 (8) | stage[slot2: halfY only] | SBAR BAR
//   phC: Q3 | stage[B-pair]              | SBAR BAR
//   phD: Q4 | stage[A0] | VMCNT6/0       | SBAR BAR
// Stage slots / vmcnt(6) FIFO identical to R3 (verified: 14 outstanding at
// each VMCNT6, oldest 8 = the tile consumed next; WAR gap >= 1 full phase
// after the overwritten region's last waited read).

__device__ __forceinline__ bf16x8 ldsfrag(const char* region, int row, int cb) {
  return *(const bf16x8*)(region + row * 128 + (cb ^ ((row & 7) << 4)));
}

template<int LDK>
__device__ __forceinline__ void stage_half(const bf16_t* gsrc, char* ldsreg, int t) {
  #pragma unroll
  for (int j = 0; j < 2; ++j) {
    const int idx = j * 512 + t;          // 1024 x 16B = 128 rows x 64 cols bf16
    const int row = idx >> 3;
    const int cb  = ((idx & 7) << 4) ^ ((row & 7) << 4);   // inverse-swizzled src col
    __builtin_amdgcn_global_load_lds(AS1((const char*)(gsrc + (int64_t)row * LDK) + cb),
                                     AS3(ldsreg + idx * 16), 16, 0, 0);
  }
}

#define MFMA_QUAD(AF, BF, MO, NO) \
  do { _Pragma("unroll") for (int m_ = 0; m_ < 4; ++m_) \
       _Pragma("unroll") for (int n_ = 0; n_ < 2; ++n_) \
       _Pragma("unroll") for (int k_ = 0; k_ < 2; ++k_) \
         acc[(MO) + m_][(NO) + n_] = __builtin_amdgcn_mfma_f32_16x16x32_bf16( \
             AF[m_][k_], BF[n_][k_], acc[(MO) + m_][(NO) + n_], 0, 0, 0); } while (0)

#define READ_A4(DST, REG, MO) \
  do { _Pragma("unroll") for (int m_ = 0; m_ < 4; ++m_) \
       _Pragma("unroll") for (int k_ = 0; k_ < 2; ++k_) \
         DST[m_][k_] = ldsfrag(REG, wm * 128 + ((MO) + m_) * 16 + fr, k_ * 64 + hi * 16); } while (0)

#define READ_B2(DST, REG, NO) \
  do { _Pragma("unroll") for (int n_ = 0; n_ < 2; ++n_) \
       _Pragma("unroll") for (int k_ = 0; k_ < 2; ++k_) \
         DST[n_][k_] = ldsfrag(REG, wn * 64 + ((NO) + n_) * 16 + fr, k_ * 64 + hi * 16); } while (0)

#define BAR()   __builtin_amdgcn_s_barrier()
#define SBAR()  __builtin_amdgcn_sched_barrier(0)
#define PRIO(x) __builtin_amdgcn_s_setprio(x)
#define VMCNT6() asm volatile("s_waitcnt vmcnt(6)" ::: "memory")
#define VMCNT0() asm volatile("s_waitcnt vmcnt(0)" ::: "memory")

template<bool RELU, bool OUT_BF16, int KK, int NN>
__global__ __launch_bounds__(512, 2)
void ffgemm8_kernel(const bf16_t* __restrict__ A, const bf16_t* __restrict__ Bt,
                    const float* __restrict__ bias, void* __restrict__ outv, int M) {
  static_assert(KK % 128 == 0, "need even number of 64-wide K tiles");
  __shared__ __align__(16) char smem[131072];
  char* const At0 = smem;
  char* const At1 = smem + 32768;
  char* const Bs0 = smem + 65536;
  char* const Bs1 = smem + 98304;

  const int t = threadIdx.x, lane = t & 63, w = t >> 6;
  const int wm = w >> 2, wn = w & 3;          // 2M x 4N wave grid
  const int fr = lane & 15, hi = lane >> 4;

  // T1: bijective XCD swizzle (nwg % 8 == 0) + 4-row supertile banding for L2
  const int gx = gridDim.x, gy = gridDim.y;
  const int nwg = gx * gy * (int)gridDim.z;
  const int id  = ((int)blockIdx.z * gy + (int)blockIdx.y) * gx + (int)blockIdx.x;
  const int swz = (id & 7) * (nwg >> 3) + (id >> 3);
  const int per_p = gx * gy;
  const int p  = swz / per_p;
  const int q  = swz % per_p;
  const int band = q / (gx * 4), qq = q % (gx * 4);
  const int bx = qq >> 2, by = band * 4 + (qq & 3);

  const int tile_m = by * 256, tile_n = bx * 256;
  const bf16_t* Ab = A  + (int64_t)p * M  * KK + (int64_t)tile_m * KK;
  const bf16_t* Bb = Bt + (int64_t)p * NN * KK + (int64_t)tile_n * KK;
  const float* biasp = bias + (int64_t)p * NN;

  f32x4 acc[8][4] = {};
  constexpr int NI = KK / 128;

  // ---- prologue: tile0 (A0,A1,B0,B1) -> buf0; tile1 (B0,B1,A0) -> buf1 ----
  stage_half<KK>(Ab,                          At0,          t);
  stage_half<KK>(Ab + (int64_t)128 * KK,      At0 + 16384,  t);
  stage_half<KK>(Bb,                          Bs0,          t);
  stage_half<KK>(Bb + (int64_t)128 * KK,      Bs0 + 16384,  t);
  stage_half<KK>(Bb + 64,                     Bs1,          t);
  stage_half<KK>(Bb + (int64_t)128 * KK + 64, Bs1 + 16384,  t);
  stage_half<KK>(Ab + 64,                     At1,          t);
  VMCNT6();          // retire tile0's 8 loads; tile1's B0,B1,A0 (6) in flight
  BAR(); SBAR();

  for (int i = 0; i < NI; ++i) {
    const int k0 = i * 128;                  // tile 2i @ k0, tile 2i+1 @ k0+64
    const bool more = (i < NI - 1);
    bf16x8 a0[4][2], a1[4][2], b0[2][2], b1[2][2];

    // ===== half X: tile 2i from buf0 =====
    // phA: boundary reads | Q1 | read b1 | stage At1b: A1(t2i+1)
    READ_A4(a0, At0, 0); READ_B2(b0, Bs0, 0);
    PRIO(1); MFMA_QUAD(a0, b0, 0, 0); PRIO(0);
    READ_B2(b1, Bs0, 2);
    stage_half<KK>(Ab + (int64_t)128 * KK + (k0 + 64), At1 + 16384, t);
    SBAR(); BAR();
    // phB: Q2 | read a1
    PRIO(1); MFMA_QUAD(a0, b1, 0, 2); PRIO(0);
    READ_A4(a1, At0, 4);
    SBAR(); BAR();
    // phC: Q3 | stage Bs0: B0,B1(t2i+2)
    PRIO(1); MFMA_QUAD(a1, b0, 4, 0); PRIO(0);
    if (more) { stage_half<KK>(Bb + (k0 + 128), Bs0, t);
                stage_half<KK>(Bb + (int64_t)128 * KK + (k0 + 128), Bs0 + 16384, t); }
    SBAR(); BAR();
    // phD: Q4 | stage At0a: A0(t2i+2) | vmcnt retires tile 2i+1
    PRIO(1); MFMA_QUAD(a1, b1, 4, 2); PRIO(0);
    if (more) stage_half<KK>(Ab + (k0 + 128), At0, t);
    if (more) VMCNT6(); else VMCNT0();
    SBAR(); BAR();

    // ===== half Y: tile 2i+1 from buf1 =====
    // phA': boundary reads | Q1' | read b1' | stage At0b: A1(t2i+2)
    READ_A4(a0, At1, 0); READ_B2(b0, Bs1, 0);
    PRIO(1); MFMA_QUAD(a0, b0, 0, 0); PRIO(0);
    READ_B2(b1, Bs1, 2);
    if (more) stage_half<KK>(Ab + (int64_t)128 * KK + (k0 + 128), At0 + 16384, t);
    SBAR(); BAR();
    // phB': Q2' | read a1'
    PRIO(1); MFMA_QUAD(a0, b1, 0, 2); PRIO(0);
    READ_A4(a1, At1, 4);
    SBAR(); BAR();
    // phC': Q3' | stage Bs1: B0,B1(t2i+3)
    PRIO(1); MFMA_QUAD(a1, b0, 4, 0); PRIO(0);
    if (more) { stage_half<KK>(Bb + (k0 + 192), Bs1, t);
                stage_half<KK>(Bb + (int64_t)128 * KK + (k0 + 192), Bs1 + 16384, t); }
    SBAR(); BAR();
    // phD': Q4' | stage At1a: A0(t2i+3) | vmcnt retires tile 2i+2
    PRIO(1); MFMA_QUAD(a1, b1, 4, 2); PRIO(0);
    if (more) stage_half<KK>(Ab + (k0 + 192), At1, t);
    if (more) VMCNT6(); else VMCNT0();
    SBAR(); BAR();
  }

  // ---- epilogue: C/D layout col=lane&15, row=(lane>>4)*4+j ----
  float bv[4];
  #pragma unroll
  for (int n = 0; n < 4; ++n) bv[n] = biasp[tile_n + wn * 64 + n * 16 + fr];
  if (OUT_BF16) {
    bf16_t* out = (bf16_t*)outv + (int64_t)p * M * NN;
    #pragma unroll
    for (int m = 0; m < 8; ++m)
      #pragma unroll
      for (int j = 0; j < 4; ++j) {
        const int row = tile_m + wm * 128 + m * 16 + hi * 4 + j;
        #pragma unroll
        for (int n = 0; n < 4; ++n) {
          const int col = tile_n + wn * 64 + n * 16 + fr;
          float v = acc[m][n][j] + bv[n];
          if (RELU) v = fmaxf(v, 0.0f);
          out[(int64_t)row * NN + col] = (bf16_t)v;
        }
      }
  } else {
    float* out = (float*)outv;
    #pragma unroll
    for (int m = 0; m < 8; ++m)
      #pragma unroll
      for (int j = 0; j < 4; ++j) {
        const int row = tile_m + wm * 128 + m * 16 + hi * 4 + j;
        const int grow = ((row >> 8) << 10) + p * SPP + (row & 255);
        #pragma unroll
        for (int n = 0; n < 4; ++n) {
          const int col = tile_n + wn * 64 + n * 16 + fr;
          out[(int64_t)grow * NN + col] = acc[m][n][j] + bv[n];
        }
      }
  }
}

extern "C" void kernel_launch(void* const* d_in, const int* in_sizes, int n_in,
                              void* d_out, int out_size, void* d_ws, size_t ws_size,
                              hipStream_t stream) {
  (void)in_sizes; (void)n_in; (void)out_size; (void)ws_size;
  const float* x  = (const float*)d_in[0];
  const float* W1 = (const float*)d_in[1];
  const float* b1 = (const float*)d_in[2];
  const float* W2 = (const float*)d_in[3];
  const float* b2 = (const float*)d_in[4];
  // d_in[5] = phases: unused — static contiguous equal partition (reshape).
  float* y = (float*)d_out;

  char* ws = (char*)d_ws;
  bf16_t* xg = (bf16_t*)ws;                                   // 64 MiB  [P][8192][1024] bf16
  bf16_t* wt = (bf16_t*)(ws + (size_t)64 * 1024 * 1024);      // 32 MiB  [N][K] bf16 (W1t then W2t)
  bf16_t* h  = (bf16_t*)(ws + (size_t)96 * 1024 * 1024);      // 256 MiB [P][8192][4096] bf16

  conv_x_kernel<<<2048, 256, 0, stream>>>(x, xg);
  conv_wt_kernel<<<dim3(F_ / 32, D_ / 32, P_), 256, 0, stream>>>(W1, wt, D_, F_);
  ffgemm8_kernel<true, true, 1024, 4096><<<dim3(F_ / 256, MP / 256, P_), 512, 0, stream>>>(
      xg, wt, b1, h, MP);
  conv_wt_kernel<<<dim3(D_ / 32, F_ / 32, P_), 256, 0, stream>>>(W2, wt, F_, D_);
  ffgemm8_kernel<false, false, 4096, 1024><<<dim3(D_ / 256, MP / 256, P_), 512, 0, stream>>>(
      h, wt, b2, y, MP);
}